// Round 8
// baseline (127.599 us; speedup 1.0000x reference)
//
#include <hip/hip_runtime.h>

// SparseLoRAMoE, expert-grouped, atomic-free.
// Round-8: k2 keeps r4's E=4 compute skeleton (wave owns 4 entries x 16 ranks,
// lanes split K, acc[64], 64-lane butterfly) but stages wa through LDS with
// async global_load_lds (width 16), double-buffered, 1 barrier/K-step.
//   Why: r4/r7's k2 held wa in wv[16] float4 regs -> ~180 VGPR -> (256,2) ->
//   2 waves/SIMD -> L2 latency on the 16 wa loads exposed (VALUBusy ~15%).
//   LDS staging kills the wv registers: ~120 live VGPR, (256,3), 12 waves/CU,
//   and each wa byte crosses L1 once per block instead of once per wave.
//   ds_read_b128 at linear stride-16B = measured conflict-free pattern.
//   FMA floor 3.4us; x HBM stream 32MB ~5us; target k2 ~6-9us.
//   K1 (272 blocks): per-bucket scan of idxs, LDS counter, no global atomics.
//   K3 (1024 blocks): 2 cols/thread, LDS-staged bucket, non-temporal stores.
// No zeroing, no global atomics on out, bit-deterministic output.

#define NDIM   2048
#define RANK   16
#define NEXP   16
#define TOKENS 4096
#define CAP_E  768      // per-expert entries; mean 512, sd ~22 -> +11 sigma
#define CAP_P  64       // per-pair tokens;   mean 16,  sd ~4  -> +12 sigma
#define TILE_E 16       // entries per K2 block (4 waves x 4)
#define ETILES (CAP_E / TILE_E)   // 48
#define CHUNKF 256      // K-slice floats per step

#define DOT4(a, b) ((a).x*(b).x + (a).y*(b).y + (a).z*(b).z + (a).w*(b).w)

// async 16B/lane global->LDS: lds base must be wave-uniform; HW writes
// lane i at base + i*16; global src is per-lane.
__device__ __forceinline__ void load_lds16(const float* g, float* lds_base) {
    __builtin_amdgcn_global_load_lds(
        (const __attribute__((address_space(1))) void*)g,
        (__attribute__((address_space(3))) void*)lds_base,
        16, 0, 0);
}

// ---------------- K1: bucketing, one block per bucket ----------------
__global__ __launch_bounds__(256) void k1_bucket(const int* __restrict__ idxs,
                                                 int* __restrict__ cntE,
                                                 int* __restrict__ cntP,
                                                 int* __restrict__ bucketE,
                                                 int* __restrict__ bucketP) {
    __shared__ int lcnt;
    const int bid = blockIdx.x;
    const int tid = threadIdx.x;
    if (tid == 0) lcnt = 0;
    __syncthreads();

    if (bid < NEXP) {                       // expert bucket: entries i with idxs[i]==e
        const int e = bid;
        const int4* p4 = (const int4*)idxs; // 8192 ints -> 2048 int4
        int* bk = bucketE + e * CAP_E;
        for (int i = tid; i < TOKENS * 2 / 4; i += 256) {
            int4 v = p4[i];
            if (v.x == e) { int p = atomicAdd(&lcnt, 1); if (p < CAP_E) bk[p] = 4*i+0; }
            if (v.y == e) { int p = atomicAdd(&lcnt, 1); if (p < CAP_E) bk[p] = 4*i+1; }
            if (v.z == e) { int p = atomicAdd(&lcnt, 1); if (p < CAP_E) bk[p] = 4*i+2; }
            if (v.w == e) { int p = atomicAdd(&lcnt, 1); if (p < CAP_E) bk[p] = 4*i+3; }
        }
        __syncthreads();
        if (tid == 0) cntE[e] = lcnt < CAP_E ? lcnt : CAP_E;
    } else {                                // pair bucket: tokens t with (e0,e1)==pb
        const int pb = bid - NEXP;
        const int e0 = pb >> 4, e1 = pb & (NEXP - 1);
        const int2* p2 = (const int2*)idxs;
        int* bk = bucketP + pb * CAP_P;
        for (int t = tid; t < TOKENS; t += 256) {
            int2 v = p2[t];
            if (v.x == e0 && v.y == e1) {
                int p = atomicAdd(&lcnt, 1);
                if (p < CAP_P) bk[p] = t;
            }
        }
        __syncthreads();
        if (tid == 0) cntP[pb] = lcnt < CAP_P ? lcnt : CAP_P;
    }
}

// ---------------- K2: stage A, LDS-staged wa (dbuf), E=4, acc[64] ----------------
__global__ __launch_bounds__(256, 3) void k2_stage_a(const float* __restrict__ x,
                                                     const float* __restrict__ wa,
                                                     const int* __restrict__ cntE,
                                                     const int* __restrict__ bucketE,
                                                     float* __restrict__ acts) {
    const int e    = blockIdx.x & (NEXP - 1);
    const int tile = blockIdx.x >> 4;           // 0..ETILES-1
    int n = cntE[e];
    const int start = tile * TILE_E;
    int m = n - start;
    if (m <= 0) return;
    if (m > TILE_E) m = TILE_E;

    __shared__ int sTok[TILE_E];
    __shared__ __align__(16) float was[2][RANK][CHUNKF];   // 32 KB double buffer

    const int tid  = threadIdx.x;
    const int lane = tid & 63;
    const int wave = tid >> 6;

    if (tid < TILE_E) {
        int src = tid < m ? tid : m - 1;        // duplicate last entry in short tiles
        sTok[tid] = bucketE[e * CAP_E + start + src];
    }

    const float* wae = wa + (size_t)e * RANK * NDIM;
    // prologue: stage slice 0; wave w owns rank rows 4w..4w+3 (uniform lds base)
    #pragma unroll
    for (int q = 0; q < 4; q++) {
        const int r = 4 * wave + q;
        load_lds16(wae + (size_t)r * NDIM + lane * 4, &was[0][r][0]);
    }
    __syncthreads();                            // sTok + slice-0 stage complete

    const float* xp[4];
    #pragma unroll
    for (int j = 0; j < 4; j++)
        xp[j] = x + (size_t)(sTok[wave * 4 + j] >> 1) * NDIM + lane * 4;

    float acc[64];
    #pragma unroll
    for (int i = 0; i < 64; i++) acc[i] = 0.f;

    #pragma unroll 2
    for (int s = 0; s < NDIM / CHUNKF; s++) {   // 8 K-steps
        const int cur = s & 1, nxt = cur ^ 1;
        if (s < NDIM / CHUNKF - 1) {            // issue next-slice stage (async)
            #pragma unroll
            for (int q = 0; q < 4; q++) {
                const int r = 4 * wave + q;
                load_lds16(wae + (size_t)r * NDIM + (s + 1) * CHUNKF + lane * 4,
                           &was[nxt][r][0]);
            }
        }
        float4 xv0 = *(const float4*)(xp[0] + s * CHUNKF);
        float4 xv1 = *(const float4*)(xp[1] + s * CHUNKF);
        float4 xv2 = *(const float4*)(xp[2] + s * CHUNKF);
        float4 xv3 = *(const float4*)(xp[3] + s * CHUNKF);
        #pragma unroll
        for (int r4 = 0; r4 < RANK; r4 += 4) {  // 4 ranks at a time from LDS
            float4 w0 = *(const float4*)&was[cur][r4 + 0][lane * 4];
            float4 w1 = *(const float4*)&was[cur][r4 + 1][lane * 4];
            float4 w2 = *(const float4*)&was[cur][r4 + 2][lane * 4];
            float4 w3 = *(const float4*)&was[cur][r4 + 3][lane * 4];
            acc[r4 + 0]      += DOT4(xv0, w0);
            acc[r4 + 1]      += DOT4(xv0, w1);
            acc[r4 + 2]      += DOT4(xv0, w2);
            acc[r4 + 3]      += DOT4(xv0, w3);
            acc[16 + r4 + 0] += DOT4(xv1, w0);
            acc[16 + r4 + 1] += DOT4(xv1, w1);
            acc[16 + r4 + 2] += DOT4(xv1, w2);
            acc[16 + r4 + 3] += DOT4(xv1, w3);
            acc[32 + r4 + 0] += DOT4(xv2, w0);
            acc[32 + r4 + 1] += DOT4(xv2, w1);
            acc[32 + r4 + 2] += DOT4(xv2, w2);
            acc[32 + r4 + 3] += DOT4(xv2, w3);
            acc[48 + r4 + 0] += DOT4(xv3, w0);
            acc[48 + r4 + 1] += DOT4(xv3, w1);
            acc[48 + r4 + 2] += DOT4(xv3, w2);
            acc[48 + r4 + 3] += DOT4(xv3, w3);
        }
        __syncthreads();    // drains stage DMA; protects cur from next overwrite
    }

    // 64-value -> per-lane halving butterfly (all static indices, stays in VGPRs)
    #pragma unroll
    for (int mw = 32; mw >= 1; mw >>= 1) {
        const bool up = (lane & mw) != 0;
        #pragma unroll
        for (int i = 0; i < mw; i++) {
            float lo = acc[i], hi = acc[i + mw];
            float mine = up ? hi : lo;
            float give = up ? lo : hi;
            acc[i] = mine + __shfl_xor(give, mw, 64);
        }
    }
    // lane l holds dot for entry sTok[wave*4 + (l>>4)], rank l&15
    float v  = acc[0];
    float sv = v / (1.f + __expf(-v));          // silu
    int ent  = sTok[(wave << 2) + (lane >> 4)];
    acts[(size_t)ent * RANK + (lane & 15)] = sv;
}

// ---------------- K3: stage B, 2 cols/thread, LDS-staged bucket, NT stores ----------------
__global__ __launch_bounds__(256, 2) void k3_stage_b(const float* __restrict__ routing,
                                                     const float* __restrict__ wb,
                                                     const int* __restrict__ cntP,
                                                     const int* __restrict__ bucketP,
                                                     const float* __restrict__ acts,
                                                     float* __restrict__ out) {
    const int pb  = blockIdx.x & (NEXP * NEXP - 1);
    const int dch = blockIdx.x >> 8;            // 0..3 (512 cols per block)
    int m = cntP[pb];
    if (m <= 0) return;
    if (m > CAP_P) m = CAP_P;
    const int e0 = pb >> 4;
    const int e1 = pb & (NEXP - 1);
    const int tid = threadIdx.x;
    const int d0 = dch * 512 + tid;
    const int d1 = d0 + 256;

    __shared__ float sacts[CAP_P][2 * RANK];    // 8 KB
    __shared__ float srout[CAP_P][2];
    __shared__ int   stok[CAP_P];

    const int* bp = bucketP + pb * CAP_P;
    if (tid < m) {
        int t = bp[tid];
        stok[tid] = t;
        srout[tid][0] = routing[2 * t];
        srout[tid][1] = routing[2 * t + 1];
    }
    __syncthreads();
    for (int idx = tid; idx < m * 8; idx += 256) {
        int tok = idx >> 3, q = idx & 7;
        float4 v = *(const float4*)(acts + (size_t)stok[tok] * 2 * RANK + q * 4);
        *(float4*)&sacts[tok][q * 4] = v;
    }
    __syncthreads();

    // wb cols for BOTH experts at BOTH d0,d1: 16 float4 = 64 VGPRs, reused over bucket
    const float4* p00 = (const float4*)(wb + ((size_t)e0 * NDIM + d0) * RANK);
    const float4* p01 = (const float4*)(wb + ((size_t)e0 * NDIM + d1) * RANK);
    const float4* p10 = (const float4*)(wb + ((size_t)e1 * NDIM + d0) * RANK);
    const float4* p11 = (const float4*)(wb + ((size_t)e1 * NDIM + d1) * RANK);
    const float4 a00 = p00[0], a01 = p00[1], a02 = p00[2], a03 = p00[3];
    const float4 b00 = p01[0], b01 = p01[1], b02 = p01[2], b03 = p01[3];
    const float4 a10 = p10[0], a11 = p10[1], a12 = p10[2], a13 = p10[3];
    const float4 b10 = p11[0], b11 = p11[1], b12 = p11[2], b13 = p11[3];

    #pragma unroll 2
    for (int i = 0; i < m; i++) {
        const float4* a = (const float4*)sacts[i];      // LDS broadcast reads
        float4 A0 = a[0], A1 = a[1], A2 = a[2], A3 = a[3];
        float4 B0 = a[4], B1 = a[5], B2 = a[6], B3 = a[7];
        float s0_0 = DOT4(a00, A0) + DOT4(a01, A1) + DOT4(a02, A2) + DOT4(a03, A3);
        float s1_0 = DOT4(a10, B0) + DOT4(a11, B1) + DOT4(a12, B2) + DOT4(a13, B3);
        float s0_1 = DOT4(b00, A0) + DOT4(b01, A1) + DOT4(b02, A2) + DOT4(b03, A3);
        float s1_1 = DOT4(b10, B0) + DOT4(b11, B1) + DOT4(b12, B2) + DOT4(b13, B3);
        const float r0 = srout[i][0], r1 = srout[i][1];
        float* op = out + (size_t)stok[i] * NDIM;
        __builtin_nontemporal_store(2.0f * (r0 * s0_0 + r1 * s1_0), op + d0);
        __builtin_nontemporal_store(2.0f * (r0 * s0_1 + r1 * s1_1), op + d1);
    }
}

extern "C" void kernel_launch(void* const* d_in, const int* in_sizes, int n_in,
                              void* d_out, int out_size, void* d_ws, size_t ws_size,
                              hipStream_t stream) {
    const float* x       = (const float*)d_in[0];
    const float* routing = (const float*)d_in[1];
    const int*   idxs    = (const int*)  d_in[2];
    const float* wa      = (const float*)d_in[3];
    const float* wb      = (const float*)d_in[4];
    float*       out     = (float*)d_out;

    // ws layout (bytes): [cntE 64][cntP @64][bucketE @2048 48KB]
    //                    [bucketP @51200 64KB][acts @116736 512KB]
    int*   cntE    = (int*)d_ws;
    int*   cntP    = (int*)((char*)d_ws + 64);
    int*   bucketE = (int*)((char*)d_ws + 2048);
    int*   bucketP = (int*)((char*)d_ws + 2048 + NEXP * CAP_E * 4);
    float* acts    = (float*)((char*)d_ws + 2048 + NEXP * CAP_E * 4
                                          + NEXP * NEXP * CAP_P * 4);

    k1_bucket <<<NEXP + NEXP * NEXP, 256, 0, stream>>>(idxs, cntE, cntP, bucketE, bucketP);
    k2_stage_a<<<NEXP * ETILES, 256, 0, stream>>>(x, wa, cntE, bucketE, acts);
    k3_stage_b<<<NEXP * NEXP * (NDIM / 512), 256, 0, stream>>>(routing, wb, cntP,
                                                               bucketP, acts, out);
}